// Round 1
// baseline (2379.558 us; speedup 1.0000x reference)
//
#include <hip/hip_runtime.h>
#include <math.h>

typedef __attribute__((ext_vector_type(8))) short bf16x8;
typedef __attribute__((ext_vector_type(4))) float f32x4;
typedef __attribute__((ext_vector_type(4))) float float4v;
typedef __attribute__((ext_vector_type(2))) float float2v;
typedef __attribute__((ext_vector_type(4))) unsigned short ushort4v;

#define N_TOK 1024
#define D_DIM 64
#define BMt 128
#define BNt 128
#define BKt 32
#define KP 72   // K LDS pitch (ushorts): 144B rows -> 16B-class = (9m+g)%8, uniform
#define SP 40   // S / Vt LDS pitch (ushorts): 80B rows -> 16B-class = (5n+g)%8, uniform

__device__ __forceinline__ unsigned short f2bf(float f) {
    union { float f; unsigned u; } v; v.f = f;
    return (unsigned short)((v.u + 0x7fffu + ((v.u >> 16) & 1u)) >> 16);
}
__device__ __forceinline__ float bf2f(unsigned short h) {
    union { unsigned u; float f; } v; v.u = ((unsigned)h) << 16;
    return v.f;
}
__device__ __forceinline__ float phif(float x) {
    // elu(x)+1 : x>0 -> x+1 ; x<=0 -> exp(x)
    return x > 0.0f ? x + 1.0f : __expf(x);
}

__global__ __launch_bounds__(256)
void ka_fused(const float* __restrict__ Qp, const float* __restrict__ Kp,
              const float* __restrict__ Vp, float* __restrict__ Op)
{
    __shared__ unsigned short KhiS[32][KP], KloS[32][KP];
    __shared__ unsigned short VthiS[128][SP], VtloS[128][SP];
    __shared__ unsigned short ShiS[128][SP], SloS[128][SP];

    const int tid  = threadIdx.x;
    const int lane = tid & 63;
    const int wid  = tid >> 6;
    const int wr   = wid >> 1;     // wave row (0..1) -> 64 output rows
    const int wc   = wid & 1;      // wave col (0..1) -> 64 output cols
    const int lr   = lane & 15;    // intra-frag row/col
    const int lg   = lane >> 4;    // intra-frag k-group
    const int j0   = blockIdx.x * BNt;
    const int i0   = blockIdx.y * BMt;
    const int bh   = blockIdx.z;

    const size_t qkbase = (size_t)bh * N_TOK * D_DIM;
    const size_t vbase  = (size_t)bh * N_TOK * N_TOK;

    const f32x4 fzero = {0.f, 0.f, 0.f, 0.f};

    // ---- Q fragments for S-compute: wave `wid` owns S rows [wid*32, wid*32+32) ----
    bf16x8 qhi[2][2], qlo[2][2];
    #pragma unroll
    for (int fr = 0; fr < 2; ++fr) {
        #pragma unroll
        for (int kb = 0; kb < 2; ++kb) {
            const float* src = Qp + qkbase
                + (size_t)(i0 + wid * 32 + fr * 16 + lr) * D_DIM + kb * 32 + lg * 8;
            float4v a = *(const float4v*)src;
            float4v b = *(const float4v*)(src + 4);
            float x[8] = {a[0], a[1], a[2], a[3], b[0], b[1], b[2], b[3]};
            bf16x8 h, l;
            #pragma unroll
            for (int e = 0; e < 8; ++e) {
                float p = phif(x[e]);
                unsigned short hh = f2bf(p);
                h[e] = (short)hh;
                l[e] = (short)f2bf(p - bf2f(hh));
            }
            qhi[fr][kb] = h;
            qlo[fr][kb] = l;
        }
    }

    f32x4 acc[4][4];
    #pragma unroll
    for (int a = 0; a < 4; ++a)
        #pragma unroll
        for (int b = 0; b < 4; ++b)
            acc[a][b] = fzero;

    for (int ms = 0; ms < N_TOK / BKt; ++ms) {
        const int m0 = ms * BKt;
        __syncthreads();   // previous iteration's LDS reads complete

        // ---- stage phi(K) rows m0..m0+32 into K LDS (hi/lo) ----
        #pragma unroll
        for (int r2 = 0; r2 < 2; ++r2) {
            int f   = tid + r2 * 256;        // float4 index 0..511
            int row = f >> 4;                // 16 float4 per 64-wide row
            int dq  = (f & 15) * 4;
            float4v v = *(const float4v*)(Kp + qkbase + (size_t)(m0 + row) * D_DIM + dq);
            ushort4v h, l;
            #pragma unroll
            for (int e = 0; e < 4; ++e) {
                float p = phif(v[e]);
                h[e] = f2bf(p);
                l[e] = f2bf(p - bf2f(h[e]));
            }
            *(ushort4v*)&KhiS[row][dq] = h;
            *(ushort4v*)&KloS[row][dq] = l;
        }

        // ---- stage V^T (hi/lo) : V[m0..m0+32][j0..j0+128] -> Vt[n][m] ----
        {
            int c2 = tid & 63;               // n-pair index
            int mh = tid >> 6;               // m-subrange mh*8..+8
            int n  = 2 * c2;
            float va[8], vb[8];
            #pragma unroll
            for (int r = 0; r < 8; ++r) {
                float2v t = *(const float2v*)(Vp + vbase
                    + (size_t)(m0 + mh * 8 + r) * N_TOK + j0 + n);
                va[r] = t[0];
                vb[r] = t[1];
            }
            bf16x8 h, l;
            #pragma unroll
            for (int e = 0; e < 8; ++e) {
                unsigned short hh = f2bf(va[e]);
                h[e] = (short)hh;
                l[e] = (short)f2bf(va[e] - bf2f(hh));
            }
            *(bf16x8*)&VthiS[n][mh * 8] = h;
            *(bf16x8*)&VtloS[n][mh * 8] = l;
            #pragma unroll
            for (int e = 0; e < 8; ++e) {
                unsigned short hh = f2bf(vb[e]);
                h[e] = (short)hh;
                l[e] = (short)f2bf(vb[e] - bf2f(hh));
            }
            *(bf16x8*)&VthiS[n + 1][mh * 8] = h;
            *(bf16x8*)&VtloS[n + 1][mh * 8] = l;
        }
        __syncthreads();

        // ---- S tile (split-bf16, 3 terms): rows wid*32..+32, cols 0..32 ----
        #pragma unroll
        for (int fr = 0; fr < 2; ++fr) {
            #pragma unroll
            for (int fc = 0; fc < 2; ++fc) {
                f32x4 sa = fzero;
                #pragma unroll
                for (int kb = 0; kb < 2; ++kb) {
                    int mcol = fc * 16 + lr;
                    int d0   = kb * 32 + lg * 8;
                    bf16x8 kh = *(const bf16x8*)&KhiS[mcol][d0];
                    bf16x8 kl = *(const bf16x8*)&KloS[mcol][d0];
                    sa = __builtin_amdgcn_mfma_f32_16x16x32_bf16(qhi[fr][kb], kh, sa, 0, 0, 0);
                    sa = __builtin_amdgcn_mfma_f32_16x16x32_bf16(qhi[fr][kb], kl, sa, 0, 0, 0);
                    sa = __builtin_amdgcn_mfma_f32_16x16x32_bf16(qlo[fr][kb], kh, sa, 0, 0, 0);
                }
                // C-frag -> LDS (hi/lo split) for re-read as A-frag
                int col = fc * 16 + lr;
                int r0  = wid * 32 + fr * 16 + lg * 4;
                #pragma unroll
                for (int r = 0; r < 4; ++r) {
                    unsigned short hh = f2bf(sa[r]);
                    ShiS[r0 + r][col] = hh;
                    SloS[r0 + r][col] = f2bf(sa[r] - bf2f(hh));
                }
            }
        }
        __syncthreads();

        // ---- Num += S @ V (split-bf16, 3 terms) ----
        {
            bf16x8 sh[4], sl[4];
            int k0 = lg * 8;
            #pragma unroll
            for (int am = 0; am < 4; ++am) {
                int row = wr * 64 + am * 16 + lr;
                sh[am] = *(const bf16x8*)&ShiS[row][k0];
                sl[am] = *(const bf16x8*)&SloS[row][k0];
            }
            #pragma unroll
            for (int bn = 0; bn < 4; ++bn) {
                int col = wc * 64 + bn * 16 + lr;
                bf16x8 vh = *(const bf16x8*)&VthiS[col][k0];
                bf16x8 vl = *(const bf16x8*)&VtloS[col][k0];
                #pragma unroll
                for (int am = 0; am < 4; ++am) {
                    acc[am][bn] = __builtin_amdgcn_mfma_f32_16x16x32_bf16(sh[am], vh, acc[am][bn], 0, 0, 0);
                    acc[am][bn] = __builtin_amdgcn_mfma_f32_16x16x32_bf16(sh[am], vl, acc[am][bn], 0, 0, 0);
                    acc[am][bn] = __builtin_amdgcn_mfma_f32_16x16x32_bf16(sl[am], vh, acc[am][bn], 0, 0, 0);
                }
            }
        }
    }

    // ---- Den per 32-col chunk, divide, store ----
    for (int ch = 0; ch < 4; ++ch) {
        __syncthreads();
        // stage phi(K) rows j0 + ch*32 .. +32
        #pragma unroll
        for (int r2 = 0; r2 < 2; ++r2) {
            int f   = tid + r2 * 256;
            int row = f >> 4;
            int dq  = (f & 15) * 4;
            float4v v = *(const float4v*)(Kp + qkbase
                + (size_t)(j0 + ch * 32 + row) * D_DIM + dq);
            ushort4v h, l;
            #pragma unroll
            for (int e = 0; e < 4; ++e) {
                float p = phif(v[e]);
                h[e] = f2bf(p);
                l[e] = f2bf(p - bf2f(h[e]));
            }
            *(ushort4v*)&KhiS[row][dq] = h;
            *(ushort4v*)&KloS[row][dq] = l;
        }
        __syncthreads();

        if (wc == (ch >> 1)) {       // this chunk belongs to waves in column wc
            int bp = ch & 1;
            #pragma unroll
            for (int am = 0; am < 4; ++am) {
                // Q frags for this wave's OUTPUT rows (differ from S-compute rows)
                bf16x8 qh2[2], ql2[2];
                #pragma unroll
                for (int kb = 0; kb < 2; ++kb) {
                    const float* src = Qp + qkbase
                        + (size_t)(i0 + wr * 64 + am * 16 + lr) * D_DIM + kb * 32 + lg * 8;
                    float4v a = *(const float4v*)src;
                    float4v b = *(const float4v*)(src + 4);
                    float x[8] = {a[0], a[1], a[2], a[3], b[0], b[1], b[2], b[3]};
                    bf16x8 h, l;
                    #pragma unroll
                    for (int e = 0; e < 8; ++e) {
                        float p = phif(x[e]);
                        unsigned short hh = f2bf(p);
                        h[e] = (short)hh;
                        l[e] = (short)f2bf(p - bf2f(hh));
                    }
                    qh2[kb] = h;
                    ql2[kb] = l;
                }
                #pragma unroll
                for (int fc = 0; fc < 2; ++fc) {
                    f32x4 da = fzero;
                    #pragma unroll
                    for (int kb = 0; kb < 2; ++kb) {
                        int mcol = fc * 16 + lr;
                        int d0   = kb * 32 + lg * 8;
                        bf16x8 kh = *(const bf16x8*)&KhiS[mcol][d0];
                        bf16x8 kl = *(const bf16x8*)&KloS[mcol][d0];
                        da = __builtin_amdgcn_mfma_f32_16x16x32_bf16(qh2[kb], kh, da, 0, 0, 0);
                        da = __builtin_amdgcn_mfma_f32_16x16x32_bf16(qh2[kb], kl, da, 0, 0, 0);
                        da = __builtin_amdgcn_mfma_f32_16x16x32_bf16(ql2[kb], kh, da, 0, 0, 0);
                    }
                    int bn    = bp * 2 + fc;
                    int ocol  = j0 + wc * 64 + bn * 16 + lr;
                    int orow0 = i0 + wr * 64 + am * 16 + lg * 4;
                    #pragma unroll
                    for (int r = 0; r < 4; ++r) {
                        Op[(size_t)bh * N_TOK * N_TOK + (size_t)(orow0 + r) * N_TOK + ocol] =
                            acc[am][bn][r] / da[r];
                    }
                }
            }
        }
    }
}

extern "C" void kernel_launch(void* const* d_in, const int* in_sizes, int n_in,
                              void* d_out, int out_size, void* d_ws, size_t ws_size,
                              hipStream_t stream)
{
    const float* Q = (const float*)d_in[0];
    const float* K = (const float*)d_in[1];
    const float* V = (const float*)d_in[2];
    float* O = (float*)d_out;
    dim3 grid(N_TOK / BNt, N_TOK / BMt, 8 * 8);
    ka_fused<<<grid, 256, 0, stream>>>(Q, K, V, O);
}

// Round 2
// 1291.463 us; speedup vs baseline: 1.8425x; 1.8425x over previous
//
#include <hip/hip_runtime.h>
#include <math.h>

typedef __attribute__((ext_vector_type(8))) short bf16x8;
typedef __attribute__((ext_vector_type(4))) float f32x4;
typedef __attribute__((ext_vector_type(4))) float float4v;
typedef __attribute__((ext_vector_type(2))) float float2v;
typedef __attribute__((ext_vector_type(4))) unsigned short ushort4v;

#define N_TOK 1024
#define D_DIM 64
#define BMt 128
#define BNt 128
#define BKt 32
#define KP 72   // K LDS pitch (ushorts)
#define SP 40   // S / Vt LDS pitch (ushorts)

__device__ __forceinline__ unsigned short f2bf(float f) {
    union { float f; unsigned u; } v; v.f = f;
    return (unsigned short)((v.u + 0x7fffu + ((v.u >> 16) & 1u)) >> 16);
}
__device__ __forceinline__ float bf2f(unsigned short h) {
    union { unsigned u; float f; } v; v.u = ((unsigned)h) << 16;
    return v.f;
}
__device__ __forceinline__ float phif(float x) {
    // elu(x)+1 : x>0 -> x+1 ; x<=0 -> exp(x)
    return x > 0.0f ? x + 1.0f : __expf(x);
}

__global__ __launch_bounds__(256)
void ka_fused(const float* __restrict__ Qp, const float* __restrict__ Kp,
              const float* __restrict__ Vp, float* __restrict__ Op)
{
    __shared__ unsigned short KhiS[32][KP], KloS[32][KP];
    __shared__ unsigned short VthiS[128][SP], VtloS[128][SP];
    __shared__ unsigned short ShiS[128][SP], SloS[128][SP];

    const int tid  = threadIdx.x;
    const int lane = tid & 63;
    const int wid  = tid >> 6;
    const int wr   = wid >> 1;     // wave row (0..1) -> 64 output rows
    const int wc   = wid & 1;      // wave col (0..1) -> 64 output cols
    const int lr   = lane & 15;    // intra-frag row/col
    const int lg   = lane >> 4;    // intra-frag k-group
    const int j0   = blockIdx.x * BNt;
    const int i0   = blockIdx.y * BMt;
    const int bh   = blockIdx.z;

    const size_t qkbase = (size_t)bh * N_TOK * D_DIM;
    const size_t vbase  = (size_t)bh * N_TOK * N_TOK;

    const f32x4 fzero = {0.f, 0.f, 0.f, 0.f};

    // ---- Q fragments for S-compute: wave `wid` owns S rows [wid*32, wid*32+32) ----
    bf16x8 qhi[2][2], qlo[2][2];
    #pragma unroll
    for (int fr = 0; fr < 2; ++fr) {
        #pragma unroll
        for (int kb = 0; kb < 2; ++kb) {
            const float* src = Qp + qkbase
                + (size_t)(i0 + wid * 32 + fr * 16 + lr) * D_DIM + kb * 32 + lg * 8;
            float4v a = *(const float4v*)src;
            float4v b = *(const float4v*)(src + 4);
            float x[8] = {a[0], a[1], a[2], a[3], b[0], b[1], b[2], b[3]};
            bf16x8 h, l;
            #pragma unroll
            for (int e = 0; e < 8; ++e) {
                float p = phif(x[e]);
                unsigned short hh = f2bf(p);
                h[e] = (short)hh;
                l[e] = (short)f2bf(p - bf2f(hh));
            }
            qhi[fr][kb] = h;
            qlo[fr][kb] = l;
        }
    }

    f32x4 acc[4][4];
    #pragma unroll
    for (int a = 0; a < 4; ++a)
        #pragma unroll
        for (int b = 0; b < 4; ++b)
            acc[a][b] = fzero;

    for (int ms = 0; ms < N_TOK / BKt; ++ms) {
        const int m0 = ms * BKt;
        __syncthreads();   // previous iteration's LDS reads complete

        // ---- stage phi(K) rows m0..m0+32 into K LDS (hi/lo) ----
        #pragma unroll
        for (int r2 = 0; r2 < 2; ++r2) {
            int f   = tid + r2 * 256;        // float4 index 0..511
            int row = f >> 4;                // 16 float4 per 64-wide row
            int dq  = (f & 15) * 4;
            float4v v = *(const float4v*)(Kp + qkbase + (size_t)(m0 + row) * D_DIM + dq);
            ushort4v h, l;
            #pragma unroll
            for (int e = 0; e < 4; ++e) {
                float p = phif(v[e]);
                h[e] = f2bf(p);
                l[e] = f2bf(p - bf2f(h[e]));
            }
            *(ushort4v*)&KhiS[row][dq] = h;
            *(ushort4v*)&KloS[row][dq] = l;
        }

        // ---- stage V^T (hi/lo) : V[m0..m0+32][j0..j0+128] -> Vt[n][m] ----
        {
            int c2 = tid & 63;               // n-pair index
            int mh = tid >> 6;               // m-subrange mh*8..+8
            int n  = 2 * c2;
            float va[8], vb[8];
            #pragma unroll
            for (int r = 0; r < 8; ++r) {
                float2v t = *(const float2v*)(Vp + vbase
                    + (size_t)(m0 + mh * 8 + r) * N_TOK + j0 + n);
                va[r] = t[0];
                vb[r] = t[1];
            }
            bf16x8 h, l;
            #pragma unroll
            for (int e = 0; e < 8; ++e) {
                unsigned short hh = f2bf(va[e]);
                h[e] = (short)hh;
                l[e] = (short)f2bf(va[e] - bf2f(hh));
            }
            *(bf16x8*)&VthiS[n][mh * 8] = h;
            *(bf16x8*)&VtloS[n][mh * 8] = l;
            #pragma unroll
            for (int e = 0; e < 8; ++e) {
                unsigned short hh = f2bf(vb[e]);
                h[e] = (short)hh;
                l[e] = (short)f2bf(vb[e] - bf2f(hh));
            }
            *(bf16x8*)&VthiS[n + 1][mh * 8] = h;
            *(bf16x8*)&VtloS[n + 1][mh * 8] = l;
        }
        __syncthreads();

        // ---- S tile (split-bf16, 3 terms): rows wid*32..+32, cols 0..32 ----
        #pragma unroll
        for (int fr = 0; fr < 2; ++fr) {
            #pragma unroll
            for (int fc = 0; fc < 2; ++fc) {
                f32x4 sa = fzero;
                #pragma unroll
                for (int kb = 0; kb < 2; ++kb) {
                    int mcol = fc * 16 + lr;
                    int d0   = kb * 32 + lg * 8;
                    bf16x8 kh = *(const bf16x8*)&KhiS[mcol][d0];
                    bf16x8 kl = *(const bf16x8*)&KloS[mcol][d0];
                    sa = __builtin_amdgcn_mfma_f32_16x16x32_bf16(qhi[fr][kb], kh, sa, 0, 0, 0);
                    sa = __builtin_amdgcn_mfma_f32_16x16x32_bf16(qhi[fr][kb], kl, sa, 0, 0, 0);
                    sa = __builtin_amdgcn_mfma_f32_16x16x32_bf16(qlo[fr][kb], kh, sa, 0, 0, 0);
                }
                // C-frag -> LDS (hi/lo split) for re-read as A-frag
                int col = fc * 16 + lr;
                int r0  = wid * 32 + fr * 16 + lg * 4;
                #pragma unroll
                for (int r = 0; r < 4; ++r) {
                    unsigned short hh = f2bf(sa[r]);
                    ShiS[r0 + r][col] = hh;
                    SloS[r0 + r][col] = f2bf(sa[r] - bf2f(hh));
                }
            }
        }
        __syncthreads();

        // ---- Num += S @ V (split-bf16, 3 terms) ----
        {
            bf16x8 sh[4], sl[4];
            int k0 = lg * 8;
            #pragma unroll
            for (int am = 0; am < 4; ++am) {
                int row = wr * 64 + am * 16 + lr;
                sh[am] = *(const bf16x8*)&ShiS[row][k0];
                sl[am] = *(const bf16x8*)&SloS[row][k0];
            }
            #pragma unroll
            for (int bn = 0; bn < 4; ++bn) {
                int col = wc * 64 + bn * 16 + lr;
                bf16x8 vh = *(const bf16x8*)&VthiS[col][k0];
                bf16x8 vl = *(const bf16x8*)&VtloS[col][k0];
                #pragma unroll
                for (int am = 0; am < 4; ++am) {
                    acc[am][bn] = __builtin_amdgcn_mfma_f32_16x16x32_bf16(sh[am], vh, acc[am][bn], 0, 0, 0);
                    acc[am][bn] = __builtin_amdgcn_mfma_f32_16x16x32_bf16(sh[am], vl, acc[am][bn], 0, 0, 0);
                    acc[am][bn] = __builtin_amdgcn_mfma_f32_16x16x32_bf16(sl[am], vh, acc[am][bn], 0, 0, 0);
                }
            }
        }
    }

    // ---- Den per 32-col chunk, divide, store ----
    // FULLY UNROLLED: ch must be compile-time so acc[][] indices are static
    // (runtime bn sent the whole acc array to scratch -> 9 GB HBM writes, R1).
    #pragma unroll
    for (int ch = 0; ch < 4; ++ch) {
        __syncthreads();
        // stage phi(K) rows j0 + ch*32 .. +32
        #pragma unroll
        for (int r2 = 0; r2 < 2; ++r2) {
            int f   = tid + r2 * 256;
            int row = f >> 4;
            int dq  = (f & 15) * 4;
            float4v v = *(const float4v*)(Kp + qkbase
                + (size_t)(j0 + ch * 32 + row) * D_DIM + dq);
            ushort4v h, l;
            #pragma unroll
            for (int e = 0; e < 4; ++e) {
                float p = phif(v[e]);
                h[e] = f2bf(p);
                l[e] = f2bf(p - bf2f(h[e]));
            }
            *(ushort4v*)&KhiS[row][dq] = h;
            *(ushort4v*)&KloS[row][dq] = l;
        }
        __syncthreads();

        if (wc == (ch >> 1)) {       // this chunk belongs to waves in column wc
            const int bp = ch & 1;
            #pragma unroll
            for (int am = 0; am < 4; ++am) {
                // Q frags for this wave's OUTPUT rows (differ from S-compute rows)
                bf16x8 qh2[2], ql2[2];
                #pragma unroll
                for (int kb = 0; kb < 2; ++kb) {
                    const float* src = Qp + qkbase
                        + (size_t)(i0 + wr * 64 + am * 16 + lr) * D_DIM + kb * 32 + lg * 8;
                    float4v a = *(const float4v*)src;
                    float4v b = *(const float4v*)(src + 4);
                    float x[8] = {a[0], a[1], a[2], a[3], b[0], b[1], b[2], b[3]};
                    bf16x8 h, l;
                    #pragma unroll
                    for (int e = 0; e < 8; ++e) {
                        float p = phif(x[e]);
                        unsigned short hh = f2bf(p);
                        h[e] = (short)hh;
                        l[e] = (short)f2bf(p - bf2f(hh));
                    }
                    qh2[kb] = h;
                    ql2[kb] = l;
                }
                #pragma unroll
                for (int fc = 0; fc < 2; ++fc) {
                    f32x4 da = fzero;
                    #pragma unroll
                    for (int kb = 0; kb < 2; ++kb) {
                        int mcol = fc * 16 + lr;
                        int d0   = kb * 32 + lg * 8;
                        bf16x8 kh = *(const bf16x8*)&KhiS[mcol][d0];
                        bf16x8 kl = *(const bf16x8*)&KloS[mcol][d0];
                        da = __builtin_amdgcn_mfma_f32_16x16x32_bf16(qh2[kb], kh, da, 0, 0, 0);
                        da = __builtin_amdgcn_mfma_f32_16x16x32_bf16(qh2[kb], kl, da, 0, 0, 0);
                        da = __builtin_amdgcn_mfma_f32_16x16x32_bf16(ql2[kb], kh, da, 0, 0, 0);
                    }
                    const int bn    = bp * 2 + fc;     // compile-time now
                    int ocol  = j0 + wc * 64 + bn * 16 + lr;
                    int orow0 = i0 + wr * 64 + am * 16 + lg * 4;
                    #pragma unroll
                    for (int r = 0; r < 4; ++r) {
                        Op[(size_t)bh * N_TOK * N_TOK + (size_t)(orow0 + r) * N_TOK + ocol] =
                            acc[am][bn][r] / da[r];
                    }
                }
            }
        }
    }
}

extern "C" void kernel_launch(void* const* d_in, const int* in_sizes, int n_in,
                              void* d_out, int out_size, void* d_ws, size_t ws_size,
                              hipStream_t stream)
{
    const float* Q = (const float*)d_in[0];
    const float* K = (const float*)d_in[1];
    const float* V = (const float*)d_in[2];
    float* O = (float*)d_out;
    dim3 grid(N_TOK / BNt, N_TOK / BMt, 8 * 8);
    ka_fused<<<grid, 256, 0, stream>>>(Q, K, V, O);
}

// Round 4
// 1116.319 us; speedup vs baseline: 2.1316x; 1.1569x over previous
//
#include <hip/hip_runtime.h>
#include <math.h>

typedef __attribute__((ext_vector_type(8))) short bf16x8;
typedef __attribute__((ext_vector_type(4))) float f32x4;
typedef __attribute__((ext_vector_type(4))) float float4v;
typedef __attribute__((ext_vector_type(2))) float float2v;
typedef __attribute__((ext_vector_type(2))) unsigned uint2v;
typedef __attribute__((ext_vector_type(4))) unsigned uint4v;

#define N_TOK 1024
#define D_DIM 64
#define BMt 128
#define BNt 128
#define BKt 32
#define KP 72   // K LDS pitch (ushorts): write class (2row+c)%16 uniform, read class (lr+lg)%8 uniform
#define SP 40   // S/Vt pitch (ushorts): b64 S-writes (10lr+lg)%16 uniform, b128 reads (5lr+lg)%8 uniform

__device__ __forceinline__ float phif(float x) {
    // elu(x)+1 : x>0 -> x+1 ; x<=0 -> exp(x)
    return x > 0.0f ? x + 1.0f : __expf(x);
}
// pack bf16(a),bf16(b) (round-half-up; tie bias negligible for random data) -> u32 [lo=a,hi=b]
__device__ __forceinline__ unsigned pk2(float a, float b) {
    unsigned ua = __builtin_bit_cast(unsigned, a) + 0x8000u;
    unsigned ub = __builtin_bit_cast(unsigned, b) + 0x8000u;
    return __builtin_amdgcn_perm(ub, ua, 0x07060302u);  // bytes: [ua.2,ua.3,ub.2,ub.3]
}
// truncation pack for residuals (err <= 2^-8 * |lo| <= 2^-16 * |s|)
__device__ __forceinline__ unsigned pk2t(float a, float b) {
    return __builtin_amdgcn_perm(__builtin_bit_cast(unsigned, b),
                                 __builtin_bit_cast(unsigned, a), 0x07060302u);
}

__global__ __launch_bounds__(256)
void ka_fused(const float* __restrict__ Qp, const float* __restrict__ Kp,
              const float* __restrict__ Vp, float* __restrict__ Op)
{
    __shared__ unsigned short KhS[32][KP];                    // phi(K) hi, 4.6 KB
    __shared__ unsigned short VtS[128][SP];                   // V^T bf16, 10.2 KB
    __shared__ unsigned short ShiS[128][SP], SloS[128][SP];   // S split, [i][m] layout, 20.5 KB

    const int tid  = threadIdx.x;
    const int lane = tid & 63;
    const int wid  = tid >> 6;
    const int wr   = wid >> 1;     // wave row (0..1) -> 64 output rows
    const int wc   = wid & 1;      // wave col (0..1) -> 64 output cols
    const int lr   = lane & 15;
    const int lg   = lane >> 4;
    const int j0   = blockIdx.x * BNt;
    const int i0   = blockIdx.y * BMt;
    const int bh   = blockIdx.z;

    const size_t qkbase = (size_t)bh * N_TOK * D_DIM;
    const size_t vbase  = (size_t)bh * N_TOK * N_TOK;
    const f32x4 fzero = {0.f, 0.f, 0.f, 0.f};

    // ---- Q B-frags (cols of S^T): wave wid owns S^T cols i in [wid*32, wid*32+32) ----
    bf16x8 qh[2][2];   // [fc][kb]
    #pragma unroll
    for (int fc = 0; fc < 2; ++fc) {
        #pragma unroll
        for (int kb = 0; kb < 2; ++kb) {
            const float* src = Qp + qkbase
                + (size_t)(i0 + wid * 32 + fc * 16 + lr) * D_DIM + kb * 32 + lg * 8;
            float4v a = *(const float4v*)src;
            float4v b = *(const float4v*)(src + 4);
            uint4v w = { pk2(phif(a[0]), phif(a[1])), pk2(phif(a[2]), phif(a[3])),
                         pk2(phif(b[0]), phif(b[1])), pk2(phif(b[2]), phif(b[3])) };
            qh[fc][kb] = __builtin_bit_cast(bf16x8, w);
        }
    }

    f32x4 acc[4][4];
    #pragma unroll
    for (int a = 0; a < 4; ++a)
        #pragma unroll
        for (int b = 0; b < 4; ++b)
            acc[a][b] = fzero;

    for (int ms = 0; ms < N_TOK / BKt; ++ms) {
        const int m0 = ms * BKt;
        __syncthreads();

        // ---- stage phi(K) rows m0..m0+32 (hi only) ----
        #pragma unroll
        for (int r2 = 0; r2 < 2; ++r2) {
            int f   = tid + r2 * 256;
            int row = f >> 4;
            int dq  = (f & 15) * 4;
            float4v v = *(const float4v*)(Kp + qkbase + (size_t)(m0 + row) * D_DIM + dq);
            uint2v w = { pk2(phif(v[0]), phif(v[1])), pk2(phif(v[2]), phif(v[3])) };
            *(uint2v*)&KhS[row][dq] = w;
        }

        // ---- stage V^T bf16: mh=tid&3 varies within wave -> uniform LDS write classes ----
        {
            const int mh = tid & 3;          // m-chunk mh*8..+8
            const int c2 = tid >> 2;         // n-pair 0..63
            const float* vsrc = Vp + vbase + (size_t)(m0 + mh * 8) * N_TOK + j0 + 2 * c2;
            float va[8], vb[8];
            #pragma unroll
            for (int r = 0; r < 8; ++r) {
                float2v t = *(const float2v*)(vsrc + (size_t)r * N_TOK);
                va[r] = t[0]; vb[r] = t[1];
            }
            uint4v wa = { pk2(va[0], va[1]), pk2(va[2], va[3]), pk2(va[4], va[5]), pk2(va[6], va[7]) };
            uint4v wb = { pk2(vb[0], vb[1]), pk2(vb[2], vb[3]), pk2(vb[4], vb[5]), pk2(vb[6], vb[7]) };
            *(uint4v*)&VtS[2 * c2][mh * 8]     = wa;
            *(uint4v*)&VtS[2 * c2 + 1][mh * 8] = wb;
        }
        __syncthreads();

        // ---- S^T = mfma(K, Q): C rows = m (k-dim of GEMM2) -> b64 stores into [i][m] ----
        #pragma unroll
        for (int fr = 0; fr < 2; ++fr) {
            #pragma unroll
            for (int fc = 0; fc < 2; ++fc) {
                f32x4 sa = fzero;
                #pragma unroll
                for (int kb = 0; kb < 2; ++kb) {
                    bf16x8 ka = *(const bf16x8*)&KhS[fr * 16 + lr][kb * 32 + lg * 8];
                    sa = __builtin_amdgcn_mfma_f32_16x16x32_bf16(ka, qh[fc][kb], sa, 0, 0, 0);
                }
                // lane holds S[m = fr*16+lg*4 + r][i = wid*32+fc*16+lr], r=0..3 consecutive
                unsigned t0 = __builtin_bit_cast(unsigned, sa[0]) + 0x8000u;
                unsigned t1 = __builtin_bit_cast(unsigned, sa[1]) + 0x8000u;
                unsigned t2 = __builtin_bit_cast(unsigned, sa[2]) + 0x8000u;
                unsigned t3 = __builtin_bit_cast(unsigned, sa[3]) + 0x8000u;
                uint2v hv = { __builtin_amdgcn_perm(t1, t0, 0x07060302u),
                              __builtin_amdgcn_perm(t3, t2, 0x07060302u) };
                float l0 = sa[0] - __builtin_bit_cast(float, t0 & 0xffff0000u);
                float l1 = sa[1] - __builtin_bit_cast(float, t1 & 0xffff0000u);
                float l2 = sa[2] - __builtin_bit_cast(float, t2 & 0xffff0000u);
                float l3 = sa[3] - __builtin_bit_cast(float, t3 & 0xffff0000u);
                uint2v lv = { pk2t(l0, l1), pk2t(l2, l3) };
                const int irow = wid * 32 + fc * 16 + lr;
                const int mcol = fr * 16 + lg * 4;
                *(uint2v*)&ShiS[irow][mcol] = hv;
                *(uint2v*)&SloS[irow][mcol] = lv;
            }
        }
        __syncthreads();

        // ---- Num += (Shi + Slo) @ V ----
        {
            const int k0 = lg * 8;
            bf16x8 sh[4], sl[4];
            #pragma unroll
            for (int am = 0; am < 4; ++am) {
                int row = wr * 64 + am * 16 + lr;
                sh[am] = *(const bf16x8*)&ShiS[row][k0];
                sl[am] = *(const bf16x8*)&SloS[row][k0];
            }
            #pragma unroll
            for (int bn = 0; bn < 4; ++bn) {
                int col = wc * 64 + bn * 16 + lr;
                bf16x8 vh = *(const bf16x8*)&VtS[col][k0];
                #pragma unroll
                for (int am = 0; am < 4; ++am) {
                    acc[am][bn] = __builtin_amdgcn_mfma_f32_16x16x32_bf16(sh[am], vh, acc[am][bn], 0, 0, 0);
                    acc[am][bn] = __builtin_amdgcn_mfma_f32_16x16x32_bf16(sl[am], vh, acc[am][bn], 0, 0, 0);
                }
            }
        }
    }

    // ---- Den per 32-col chunk (1-term), divide, store. ch unrolled (static acc idx!) ----
    #pragma unroll
    for (int ch = 0; ch < 4; ++ch) {
        __syncthreads();
        #pragma unroll
        for (int r2 = 0; r2 < 2; ++r2) {
            int f   = tid + r2 * 256;
            int row = f >> 4;
            int dq  = (f & 15) * 4;
            float4v v = *(const float4v*)(Kp + qkbase
                + (size_t)(j0 + ch * 32 + row) * D_DIM + dq);
            uint2v w = { pk2(phif(v[0]), phif(v[1])), pk2(phif(v[2]), phif(v[3])) };
            *(uint2v*)&KhS[row][dq] = w;
        }
        __syncthreads();

        if (wc == (ch >> 1)) {
            const int bp = ch & 1;
            #pragma unroll
            for (int am = 0; am < 4; ++am) {
                bf16x8 qa[2];   // A-frags for this wave's OUTPUT rows
                #pragma unroll
                for (int kb = 0; kb < 2; ++kb) {
                    const float* src = Qp + qkbase
                        + (size_t)(i0 + wr * 64 + am * 16 + lr) * D_DIM + kb * 32 + lg * 8;
                    float4v a = *(const float4v*)src;
                    float4v b = *(const float4v*)(src + 4);
                    uint4v w = { pk2(phif(a[0]), phif(a[1])), pk2(phif(a[2]), phif(a[3])),
                                 pk2(phif(b[0]), phif(b[1])), pk2(phif(b[2]), phif(b[3])) };
                    qa[kb] = __builtin_bit_cast(bf16x8, w);
                }
                #pragma unroll
                for (int fc = 0; fc < 2; ++fc) {
                    f32x4 da = fzero;
                    #pragma unroll
                    for (int kb = 0; kb < 2; ++kb) {
                        bf16x8 kB = *(const bf16x8*)&KhS[fc * 16 + lr][kb * 32 + lg * 8];
                        da = __builtin_amdgcn_mfma_f32_16x16x32_bf16(qa[kb], kB, da, 0, 0, 0);
                    }
                    const int bn    = bp * 2 + fc;
                    const int ocol  = j0 + wc * 64 + bn * 16 + lr;
                    const int orow0 = i0 + wr * 64 + am * 16 + lg * 4;
                    #pragma unroll
                    for (int r = 0; r < 4; ++r) {
                        Op[(size_t)bh * N_TOK * N_TOK + (size_t)(orow0 + r) * N_TOK + ocol] =
                            acc[am][bn][r] / da[r];
                    }
                }
            }
        }
    }
}

extern "C" void kernel_launch(void* const* d_in, const int* in_sizes, int n_in,
                              void* d_out, int out_size, void* d_ws, size_t ws_size,
                              hipStream_t stream)
{
    const float* Q = (const float*)d_in[0];
    const float* K = (const float*)d_in[1];
    const float* V = (const float*)d_in[2];
    float* O = (float*)d_out;
    dim3 grid(N_TOK / BNt, N_TOK / BMt, 8 * 8);
    ka_fused<<<grid, 256, 0, stream>>>(Q, K, V, O);
}